// Round 6
// baseline (317.625 us; speedup 1.0000x reference)
//
#include <hip/hip_runtime.h>

#define B_ 4
#define T_ 4096
#define C_ 1024
#define H_ 64
#define NITEMS 2048

typedef _Float16 half8  __attribute__((ext_vector_type(8)));
typedef _Float16 half4_ __attribute__((ext_vector_type(4)));
typedef float    floatx4 __attribute__((ext_vector_type(4)));

#define MFMA16(a, b, c)  __builtin_amdgcn_mfma_f32_16x16x32_f16(a, b, c, 0, 0, 0)
#define MFMA16K(a, b, c) __builtin_amdgcn_mfma_f32_16x16x16f16(a, b, c, 0, 0, 0)
#define LO4(v) __builtin_shufflevector(v, v, 0, 1, 2, 3)
#define HI4(v) __builtin_shufflevector(v, v, 4, 5, 6, 7)

// ---------------------------------------------------------------------------
// Kernel 1: pack W into MFMA-fragment order + zero the attn work-queue ctr.
// ---------------------------------------------------------------------------
__global__ __launch_bounds__(256) void pack_w_kn(
    const float* __restrict__ Wq, const float* __restrict__ Wk,
    const float* __restrict__ Wv, _Float16* __restrict__ Wt2,
    int* __restrict__ qctr)
{
    if (blockIdx.x == 0 && threadIdx.x == 0) *qctr = 0;
    const int idx  = blockIdx.x * 256 + threadIdx.x;  // 0 .. 196607
    const int mt   = idx >> 14;
    const int j    = (idx >> 10) & 15;
    const int f    = (idx >> 9) & 1;
    const int lane = (idx >> 3) & 63;
    const int jj   = idx & 7;
    const int q = lane >> 4, c = lane & 15;
    const int k  = j * 64 + f * 32 + q * 8 + jj;
    const int hp = mt * 16 + c;                       // 0..191
    const float* W = (hp < 64) ? Wq : (hp < 128) ? Wk : Wv;
    Wt2[idx] = (_Float16)W[k * H_ + (hp & 63)];
}

// ---------------------------------------------------------------------------
// Kernel 2: fused QKV projection (unchanged).  Vpk in 16x16x16 A-frag order.
// ---------------------------------------------------------------------------
__global__ __launch_bounds__(512) void qkv_kn(
    const float* __restrict__ x, const _Float16* __restrict__ Wt2,
    _Float16* __restrict__ Qh, _Float16* __restrict__ Kpk,
    _Float16* __restrict__ Vpk)
{
    __shared__ _Float16 xs[2][32][72];                // 9216 B
    const int tid  = threadIdx.x;
    const int lane = tid & 63, w = tid >> 6;
    const int q    = lane >> 4, c = lane & 15;
    const int nt   = w & 1;                           // n-half (16 rows)
    const int mg   = w >> 1;                          // m-group (3 m-tiles)
    const int row0 = blockIdx.x * 32;

    const int srow = tid >> 4, scol = (tid & 15) * 4;
    const float* xg = x + (size_t)(row0 + srow) * C_ + scol;

    floatx4 acc[3];
    #pragma unroll
    for (int i = 0; i < 3; ++i) acc[i] = floatx4{0.f, 0.f, 0.f, 0.f};

    float4 g = *(const float4*)xg;                    // preload tile 0

    for (int j = 0; j < 16; ++j) {
        half4_ hv;
        hv[0] = (_Float16)g.x; hv[1] = (_Float16)g.y;
        hv[2] = (_Float16)g.z; hv[3] = (_Float16)g.w;
        *(half4_*)(&xs[j & 1][srow][scol]) = hv;
        __syncthreads();
        if (j < 15) g = *(const float4*)(xg + (j + 1) * 64);

        const _Float16* xrow = &xs[j & 1][nt * 16 + c][q * 8];
        const half8 b0 = *(const half8*)xrow;
        const half8 b1 = *(const half8*)(xrow + 32);

        half8 a[6];
        #pragma unroll
        for (int i = 0; i < 3; ++i) {
            const size_t fb = ((size_t)((mg * 3 + i) * 16 + j) * 2) * 512 + lane * 8;
            a[i * 2]     = *(const half8*)(Wt2 + fb);
            a[i * 2 + 1] = *(const half8*)(Wt2 + fb + 512);
        }
        #pragma unroll
        for (int i = 0; i < 3; ++i) {
            acc[i] = MFMA16(a[i * 2],     b0, acc[i]);
            acc[i] = MFMA16(a[i * 2 + 1], b1, acc[i]);
        }
    }

    const int row = row0 + nt * 16 + c;
    const int b = row >> 12, t4 = row & (T_ - 1);
    const int kt = t4 >> 6;
    const size_t tbase = ((size_t)b * 64 + kt) * 4096;
    const int mtk = (t4 >> 4) & 3;
    const int kk  = t4 & 63;

    #pragma unroll
    for (int i = 0; i < 3; ++i) {
        const int gi = mg * 3 + i;
        if (gi < 4) {                                 // Q row-major
            half4_ v;
            #pragma unroll
            for (int r = 0; r < 4; ++r) v[r] = (_Float16)acc[i][r];
            *(half4_*)(Qh + (size_t)row * H_ + gi * 16 + q * 4) = v;
        } else if (gi < 8) {                          // K fragment-packed (16x16x32 A-frag)
            half4_ v;
            #pragma unroll
            for (int r = 0; r < 4; ++r) v[r] = (_Float16)acc[i][r];
            const int e  = gi - 4;
            const int f  = e >> 1;
            const int qa = (e * 2 + (q >> 1)) & 3;
            *(half4_*)(Kpk + tbase + ((size_t)(mtk * 2 + f) * 64 + qa * 16 + c) * 8
                       + (q & 1) * 4) = v;
        } else {                                      // V 16x16x16 A-frag packed
            const int mtv = gi - 8;
            const int qa2 = (kk >> 2) & 3;
            const int h4  = (kk >> 4) & 1;
            const int f2  = kk >> 5;
            const int i2  = kk & 3;
            #pragma unroll
            for (int r = 0; r < 4; ++r) {
                const int cv = q * 4 + r;             // h & 15
                Vpk[tbase + ((size_t)(mtv * 2 + f2) * 64 + qa2 * 16 + cv) * 8
                    + h4 * 4 + i2] = (_Float16)acc[i][r];
            }
        }
    }
}

// ---------------------------------------------------------------------------
// Kernel 3: causal flash attention, QBLK=32, 4-way block split-K + dynamic
// work queue.  Round-5 counters: Occupancy 33%, MfmaUtil 8.7%, VALU 22% —
// latency-bound starvation from the 512-block grid (2 blk/CU decaying to 1).
// Now: 2048 items = (b, t32, quarter) with kt ≡ quarter (mod 4), heavy-first
// (t32 descending).  1024 resident blocks (4/CU = 32 waves/CU) loop pulling
// items from an atomic counter -> sustained occupancy + LPT balance.  Blocks
// write unnormalized partials (O, M, L); combine_kn merges 4 partials/q-tile.
// ---------------------------------------------------------------------------
__global__ __launch_bounds__(512, 8) void attn_kn(
    const _Float16* __restrict__ Qh, const _Float16* __restrict__ Kpk,
    const _Float16* __restrict__ Vpk, float* __restrict__ Opart,
    float* __restrict__ Mp, float* __restrict__ Lp, int* __restrict__ qctr)
{
    __shared__ __align__(16) char smem[36864];
    __shared__ int s_item;
    const int lane = threadIdx.x & 63;
    const int w    = threadIdx.x >> 6;                // 0..7
    const int q    = lane >> 4, c = lane & 15;

    float* Ol = (float*)smem;                         // [8][1088] (pad 17)
    float* Ml = (float*)(smem + 34816);               // [8][32]
    float* Ll = (float*)(smem + 35840);               // [8][32]

    for (;;) {
        if (threadIdx.x == 0) s_item = atomicAdd(qctr, 1);
        __syncthreads();
        const int item = s_item;
        if (item >= NITEMS) break;

        const int t32     = 127 - (item >> 4);        // heavy tiles first
        const int b       = (item >> 2) & 3;
        const int quarter = item & 3;
        const int row0 = t32 * 32;
        const int grow = b * T_ + row0;
        const int nk   = (t32 >> 1) + 1;              // 64-key tiles (last=diag)

        // Q B-frags for the two 16-query groups, pre-scaled by (1/8)*log2(e)
        const _Float16 qs = (_Float16)0.18033688f;
        half8 bq0[2], bq1[2];
        #pragma unroll
        for (int g = 0; g < 2; ++g) {
            const _Float16* qb = Qh + (size_t)(grow + g * 16 + c) * H_;
            bq0[g] = *(const half8*)(qb + q * 8);
            bq1[g] = *(const half8*)(qb + 32 + q * 8);
            bq0[g] *= qs; bq1[g] *= qs;
        }

        floatx4 o[4][2];
        #pragma unroll
        for (int i = 0; i < 4; ++i)
            #pragma unroll
            for (int g = 0; g < 2; ++g) o[i][g] = floatx4{0.f, 0.f, 0.f, 0.f};
        float m[2] = {-3.0e38f, -3.0e38f}, l[2] = {0.f, 0.f};

        for (int kt = quarter + 4 * w; kt < nk; kt += 32) {
            const int kb = kt * 64;
            const _Float16* Kt = Kpk + ((size_t)b * 64 + kt) * 4096;
            const _Float16* Vt = Vpk + ((size_t)b * 64 + kt) * 4096;
            half8 a0[4], a1[4];

            // K-frags: lane-contiguous packed loads
            #pragma unroll
            for (int mt = 0; mt < 4; ++mt) {
                a0[mt] = *(const half8*)(Kt + ((size_t)(mt * 2)     * 64 + lane) * 8);
                a1[mt] = *(const half8*)(Kt + ((size_t)(mt * 2 + 1) * 64 + lane) * 8);
            }
            floatx4 s[4][2];
            #pragma unroll
            for (int mt = 0; mt < 4; ++mt)
                #pragma unroll
                for (int g = 0; g < 2; ++g) {
                    floatx4 z = floatx4{0.f, 0.f, 0.f, 0.f};
                    z = MFMA16(a0[mt], bq0[g], z);
                    s[mt][g] = MFMA16(a1[mt], bq1[g], z);
                }
            // V-frags issued now; latency hides behind softmax
            #pragma unroll
            for (int mt = 0; mt < 4; ++mt) {
                a0[mt] = *(const half8*)(Vt + ((size_t)(mt * 2)     * 64 + lane) * 8);
                a1[mt] = *(const half8*)(Vt + ((size_t)(mt * 2 + 1) * 64 + lane) * 8);
            }

            if (kt == nk - 1) {                       // causal mask (diag tile)
                #pragma unroll
                for (int mt = 0; mt < 4; ++mt)
                    #pragma unroll
                    for (int g = 0; g < 2; ++g)
                        #pragma unroll
                        for (int r = 0; r < 4; ++r)
                            if (kb + mt * 16 + q * 4 + r > row0 + g * 16 + c)
                                s[mt][g][r] = -3.0e38f;
            }

            // online softmax per q-group; P stays in regs as 16x16x16 B-frags
            half4_ ph[2][4];
            #pragma unroll
            for (int g = 0; g < 2; ++g) {
                float mx = s[0][g][0];
                #pragma unroll
                for (int mt = 0; mt < 4; ++mt)
                    #pragma unroll
                    for (int r = 0; r < 4; ++r) mx = fmaxf(mx, s[mt][g][r]);
                mx = fmaxf(mx, __shfl_xor(mx, 16, 64));
                mx = fmaxf(mx, __shfl_xor(mx, 32, 64));
                const float mn    = fmaxf(m[g], mx);
                const float alpha = exp2f(m[g] - mn);
                float sl = 0.f;
                #pragma unroll
                for (int mt = 0; mt < 4; ++mt)
                    #pragma unroll
                    for (int r = 0; r < 4; ++r) {
                        const float ev = exp2f(s[mt][g][r] - mn);
                        sl += ev;
                        ph[g][mt][r] = (_Float16)ev;
                    }
                sl += __shfl_xor(sl, 16, 64);
                sl += __shfl_xor(sl, 32, 64);
                l[g] = l[g] * alpha + sl;
                m[g] = mn;
                #pragma unroll
                for (int mt = 0; mt < 4; ++mt) o[mt][g] *= alpha;
            }

            // O^T += V^T · P^T as 4 key-chunk 16x16x16 MFMAs per o-tile
            #pragma unroll
            for (int mt = 0; mt < 4; ++mt) {
                const half4_ v0 = LO4(a0[mt]);
                const half4_ v1 = HI4(a0[mt]);
                const half4_ v2 = LO4(a1[mt]);
                const half4_ v3 = HI4(a1[mt]);
                #pragma unroll
                for (int g = 0; g < 2; ++g) {
                    o[mt][g] = MFMA16K(v0, ph[g][0], o[mt][g]);
                    o[mt][g] = MFMA16K(v1, ph[g][1], o[mt][g]);
                    o[mt][g] = MFMA16K(v2, ph[g][2], o[mt][g]);
                    o[mt][g] = MFMA16K(v3, ph[g][3], o[mt][g]);
                }
            }
        }

        // ---- in-block combine (8 waves), write unnormalized partial ------
        __syncthreads();
        if (q == 0) { Ml[w * 32 + c] = m[0]; Ml[w * 32 + 16 + c] = m[1]; }
        __syncthreads();
        float M0 = Ml[c], M1 = Ml[16 + c];
        #pragma unroll
        for (int w2 = 1; w2 < 8; ++w2) {
            M0 = fmaxf(M0, Ml[w2 * 32 + c]);
            M1 = fmaxf(M1, Ml[w2 * 32 + 16 + c]);
        }
        const float alpha0 = exp2f(m[0] - M0);        // 0 for empty waves
        const float alpha1 = exp2f(m[1] - M1);
        if (q == 0) { Ll[w * 32 + c] = l[0] * alpha0; Ll[w * 32 + 16 + c] = l[1] * alpha1; }

        const int h0 = w * 8 + q * 2;                 // this thread's h slice
        float* Obase = Opart + (size_t)item * 2048;
        #pragma unroll
        for (int gp = 0; gp < 2; ++gp) {
            const float a = gp ? alpha1 : alpha0;
            #pragma unroll
            for (int mt = 0; mt < 4; ++mt)
                #pragma unroll
                for (int r = 0; r < 4; ++r)
                    Ol[w * 1088 + (mt * 16 + q * 4 + r) * 17 + c] = o[mt][gp][r] * a;
            __syncthreads();
            float L = 0.f;
            #pragma unroll
            for (int w2 = 0; w2 < 8; ++w2) L += Ll[w2 * 32 + gp * 16 + c];
            if (w == 0 && q == 0) {
                Mp[(size_t)item * 32 + gp * 16 + c] = gp ? M1 : M0;
                Lp[(size_t)item * 32 + gp * 16 + c] = L;
            }
            float ox = 0.f, oy = 0.f;
            #pragma unroll
            for (int w2 = 0; w2 < 8; ++w2) {
                ox += Ol[w2 * 1088 + h0 * 17 + c];
                oy += Ol[w2 * 1088 + (h0 + 1) * 17 + c];
            }
            float2 st; st.x = ox; st.y = oy;          // unnormalized partial
            *(float2*)(Obase + (size_t)(gp * 16 + c) * 64 + h0) = st;
            __syncthreads();                          // LDS reuse (next gp/item)
        }
    }
}

// ---------------------------------------------------------------------------
// Kernel 4: merge the 4 split-K partials per q-tile, normalize, write out.
// Grid 512 blocks x 256 thr; thread -> (qrow = tid>>3, h0 = (tid&7)*8).
// ---------------------------------------------------------------------------
__global__ __launch_bounds__(256) void combine_kn(
    const float* __restrict__ Opart, const float* __restrict__ Mp,
    const float* __restrict__ Lp, float* __restrict__ out)
{
    const int cb   = blockIdx.x;                      // 0..511
    const int b    = cb & 3, t32 = cb >> 2;
    const int tid  = threadIdx.x;
    const int qrow = tid >> 3;                        // 0..31
    const int h0   = (tid & 7) * 8;                   // 0..56
    const int it0  = (127 - t32) * 16 + b * 4;        // 4 consecutive items

    float Mv[4], Lv[4];
    #pragma unroll
    for (int p = 0; p < 4; ++p) {
        Mv[p] = Mp[(size_t)(it0 + p) * 32 + qrow];
        Lv[p] = Lp[(size_t)(it0 + p) * 32 + qrow];
    }
    float M = fmaxf(fmaxf(Mv[0], Mv[1]), fmaxf(Mv[2], Mv[3]));
    float L = 0.f;
    floatx4 acc0 = floatx4{0.f, 0.f, 0.f, 0.f};
    floatx4 acc1 = floatx4{0.f, 0.f, 0.f, 0.f};
    #pragma unroll
    for (int p = 0; p < 4; ++p) {
        const float a = exp2f(Mv[p] - M);             // 0 for empty chunks
        L += Lv[p] * a;
        const floatx4* src = (const floatx4*)(Opart + (size_t)(it0 + p) * 2048
                                              + (size_t)qrow * 64 + h0);
        acc0 += src[0] * a;
        acc1 += src[1] * a;
    }
    const float inv = 1.f / L;
    floatx4* dst = (floatx4*)(out + (size_t)(b * T_ + t32 * 32 + qrow) * 64 + h0);
    dst[0] = acc0 * inv;
    dst[1] = acc1 * inv;
}

extern "C" void kernel_launch(void* const* d_in, const int* in_sizes, int n_in,
                              void* d_out, int out_size, void* d_ws, size_t ws_size,
                              hipStream_t stream) {
    const float* x  = (const float*)d_in[0];
    const float* Wq = (const float*)d_in[1];
    const float* Wk = (const float*)d_in[2];
    const float* Wv = (const float*)d_in[3];
    float* out = (float*)d_out;

    _Float16* ws = (_Float16*)d_ws;
    _Float16* Wt2 = ws;                               //   192*1024 = 196608 halfs
    _Float16* Qh  = ws + 196608;                      // 16384*64  = 1048576
    _Float16* Kpk = Qh + 1048576;                     // [4][64][4096]
    _Float16* Vpk = Kpk + 1048576;                    // [4][64][4096]
    float* Opart = (float*)(ws + 3342336);            // [2048][32][64] f32 = 16 MB
    float* Mp    = Opart + 4194304;                   // [2048][32]
    float* Lp    = Mp + 65536;                        // [2048][32]
    int*   qctr  = (int*)(Lp + 65536);                // work-queue counter

    hipLaunchKernelGGL(pack_w_kn, dim3(768), dim3(256), 0, stream,
                       Wq, Wk, Wv, Wt2, qctr);
    hipLaunchKernelGGL(qkv_kn, dim3((B_ * T_) / 32), dim3(512), 0, stream,
                       x, Wt2, Qh, Kpk, Vpk);
    hipLaunchKernelGGL(attn_kn, dim3(1024), dim3(512), 0, stream,
                       Qh, Kpk, Vpk, Opart, Mp, Lp, qctr);
    hipLaunchKernelGGL(combine_kn, dim3(512), dim3(256), 0, stream,
                       Opart, Mp, Lp, out);
}

// Round 7
// 193.463 us; speedup vs baseline: 1.6418x; 1.6418x over previous
//
#include <hip/hip_runtime.h>

#define B_ 4
#define T_ 4096
#define C_ 1024
#define H_ 64
#define NITEMS 2048

typedef _Float16 half8  __attribute__((ext_vector_type(8)));
typedef _Float16 half4_ __attribute__((ext_vector_type(4)));
typedef float    floatx4 __attribute__((ext_vector_type(4)));

#define MFMA16(a, b, c)  __builtin_amdgcn_mfma_f32_16x16x32_f16(a, b, c, 0, 0, 0)
#define MFMA16K(a, b, c) __builtin_amdgcn_mfma_f32_16x16x16f16(a, b, c, 0, 0, 0)
#define LO4(v) __builtin_shufflevector(v, v, 0, 1, 2, 3)
#define HI4(v) __builtin_shufflevector(v, v, 4, 5, 6, 7)

// ---------------------------------------------------------------------------
// Kernel 1: pack W into MFMA-fragment order (lane-contiguous A-frags).
// ---------------------------------------------------------------------------
__global__ __launch_bounds__(256) void pack_w_kn(
    const float* __restrict__ Wq, const float* __restrict__ Wk,
    const float* __restrict__ Wv, _Float16* __restrict__ Wt2)
{
    const int idx  = blockIdx.x * 256 + threadIdx.x;  // 0 .. 196607
    const int mt   = idx >> 14;
    const int j    = (idx >> 10) & 15;
    const int f    = (idx >> 9) & 1;
    const int lane = (idx >> 3) & 63;
    const int jj   = idx & 7;
    const int q = lane >> 4, c = lane & 15;
    const int k  = j * 64 + f * 32 + q * 8 + jj;
    const int hp = mt * 16 + c;                       // 0..191
    const float* W = (hp < 64) ? Wq : (hp < 128) ? Wk : Wv;
    Wt2[idx] = (_Float16)W[k * H_ + (hp & 63)];
}

// ---------------------------------------------------------------------------
// Kernel 2: fused QKV projection (unchanged).  Vpk in 16x16x16 A-frag order.
// ---------------------------------------------------------------------------
__global__ __launch_bounds__(512) void qkv_kn(
    const float* __restrict__ x, const _Float16* __restrict__ Wt2,
    _Float16* __restrict__ Qh, _Float16* __restrict__ Kpk,
    _Float16* __restrict__ Vpk)
{
    __shared__ _Float16 xs[2][32][72];                // 9216 B
    const int tid  = threadIdx.x;
    const int lane = tid & 63, w = tid >> 6;
    const int q    = lane >> 4, c = lane & 15;
    const int nt   = w & 1;                           // n-half (16 rows)
    const int mg   = w >> 1;                          // m-group (3 m-tiles)
    const int row0 = blockIdx.x * 32;

    const int srow = tid >> 4, scol = (tid & 15) * 4;
    const float* xg = x + (size_t)(row0 + srow) * C_ + scol;

    floatx4 acc[3];
    #pragma unroll
    for (int i = 0; i < 3; ++i) acc[i] = floatx4{0.f, 0.f, 0.f, 0.f};

    float4 g = *(const float4*)xg;                    // preload tile 0

    for (int j = 0; j < 16; ++j) {
        half4_ hv;
        hv[0] = (_Float16)g.x; hv[1] = (_Float16)g.y;
        hv[2] = (_Float16)g.z; hv[3] = (_Float16)g.w;
        *(half4_*)(&xs[j & 1][srow][scol]) = hv;
        __syncthreads();
        if (j < 15) g = *(const float4*)(xg + (j + 1) * 64);

        const _Float16* xrow = &xs[j & 1][nt * 16 + c][q * 8];
        const half8 b0 = *(const half8*)xrow;
        const half8 b1 = *(const half8*)(xrow + 32);

        half8 a[6];
        #pragma unroll
        for (int i = 0; i < 3; ++i) {
            const size_t fb = ((size_t)((mg * 3 + i) * 16 + j) * 2) * 512 + lane * 8;
            a[i * 2]     = *(const half8*)(Wt2 + fb);
            a[i * 2 + 1] = *(const half8*)(Wt2 + fb + 512);
        }
        #pragma unroll
        for (int i = 0; i < 3; ++i) {
            acc[i] = MFMA16(a[i * 2],     b0, acc[i]);
            acc[i] = MFMA16(a[i * 2 + 1], b1, acc[i]);
        }
    }

    const int row = row0 + nt * 16 + c;
    const int b = row >> 12, t4 = row & (T_ - 1);
    const int kt = t4 >> 6;
    const size_t tbase = ((size_t)b * 64 + kt) * 4096;
    const int mtk = (t4 >> 4) & 3;
    const int kk  = t4 & 63;

    #pragma unroll
    for (int i = 0; i < 3; ++i) {
        const int gi = mg * 3 + i;
        if (gi < 4) {                                 // Q row-major
            half4_ v;
            #pragma unroll
            for (int r = 0; r < 4; ++r) v[r] = (_Float16)acc[i][r];
            *(half4_*)(Qh + (size_t)row * H_ + gi * 16 + q * 4) = v;
        } else if (gi < 8) {                          // K fragment-packed (16x16x32 A-frag)
            half4_ v;
            #pragma unroll
            for (int r = 0; r < 4; ++r) v[r] = (_Float16)acc[i][r];
            const int e  = gi - 4;
            const int f  = e >> 1;
            const int qa = (e * 2 + (q >> 1)) & 3;
            *(half4_*)(Kpk + tbase + ((size_t)(mtk * 2 + f) * 64 + qa * 16 + c) * 8
                       + (q & 1) * 4) = v;
        } else {                                      // V 16x16x16 A-frag packed
            const int mtv = gi - 8;
            const int qa2 = (kk >> 2) & 3;
            const int h4  = (kk >> 4) & 1;
            const int f2  = kk >> 5;
            const int i2  = kk & 3;
            #pragma unroll
            for (int r = 0; r < 4; ++r) {
                const int cv = q * 4 + r;             // h & 15
                Vpk[tbase + ((size_t)(mtv * 2 + f2) * 64 + qa2 * 16 + cv) * 8
                    + h4 * 4 + i2] = (_Float16)acc[i][r];
            }
        }
    }
}

// ---------------------------------------------------------------------------
// Kernel 3: causal flash attention, QBLK=32, 4-way block split-K, STATIC
// balanced pairing.  Round-6 post-mortem: __launch_bounds__(512,8) forced
// VGPR 64->32 -> massive scratch spill (~1 GB HBM traffic/dispatch, 204 us).
// Reverted to (512,4) (round 5 measured exactly 64 VGPR for this loop ->
// 4 blocks/CU co-residency is achievable: LDS 4x36.9=147<=160 KB).
// Atomic queue removed: block bid statically processes items {bid, 2047-bid}.
// Items heavy-first (work ~ 127-(item>>4)), so each pair sums to ~constant
// work: all 1024 blocks (4/CU, 32 waves/CU) stay busy until the common end.
// Partials (O,M,L unnormalized) -> combine_kn.
// ---------------------------------------------------------------------------
__global__ __launch_bounds__(512, 4) void attn_kn(
    const _Float16* __restrict__ Qh, const _Float16* __restrict__ Kpk,
    const _Float16* __restrict__ Vpk, float* __restrict__ Opart,
    float* __restrict__ Mp, float* __restrict__ Lp)
{
    __shared__ __align__(16) char smem[36864];
    const int lane = threadIdx.x & 63;
    const int w    = threadIdx.x >> 6;                // 0..7
    const int q    = lane >> 4, c = lane & 15;

    float* Ol = (float*)smem;                         // [8][1088] (pad 17)
    float* Ml = (float*)(smem + 34816);               // [8][32]
    float* Ll = (float*)(smem + 35840);               // [8][32]

    #pragma unroll 1
    for (int pass = 0; pass < 2; ++pass) {
        const int item = pass ? (NITEMS - 1 - (int)blockIdx.x) : (int)blockIdx.x;

        const int t32     = 127 - (item >> 4);        // heavy tiles first
        const int b       = (item >> 2) & 3;
        const int quarter = item & 3;
        const int row0 = t32 * 32;
        const int grow = b * T_ + row0;
        const int nk   = (t32 >> 1) + 1;              // 64-key tiles (last=diag)

        // Q B-frags for the two 16-query groups, pre-scaled by (1/8)*log2(e)
        const _Float16 qs = (_Float16)0.18033688f;
        half8 bq0[2], bq1[2];
        #pragma unroll
        for (int g = 0; g < 2; ++g) {
            const _Float16* qb = Qh + (size_t)(grow + g * 16 + c) * H_;
            bq0[g] = *(const half8*)(qb + q * 8);
            bq1[g] = *(const half8*)(qb + 32 + q * 8);
            bq0[g] *= qs; bq1[g] *= qs;
        }

        floatx4 o[4][2];
        #pragma unroll
        for (int i = 0; i < 4; ++i)
            #pragma unroll
            for (int g = 0; g < 2; ++g) o[i][g] = floatx4{0.f, 0.f, 0.f, 0.f};
        float m[2] = {-3.0e38f, -3.0e38f}, l[2] = {0.f, 0.f};

        for (int kt = quarter + 4 * w; kt < nk; kt += 32) {
            const int kb = kt * 64;
            const _Float16* Kt = Kpk + ((size_t)b * 64 + kt) * 4096;
            const _Float16* Vt = Vpk + ((size_t)b * 64 + kt) * 4096;
            half8 a0[4], a1[4];

            // K-frags: lane-contiguous packed loads
            #pragma unroll
            for (int mt = 0; mt < 4; ++mt) {
                a0[mt] = *(const half8*)(Kt + ((size_t)(mt * 2)     * 64 + lane) * 8);
                a1[mt] = *(const half8*)(Kt + ((size_t)(mt * 2 + 1) * 64 + lane) * 8);
            }
            floatx4 s[4][2];
            #pragma unroll
            for (int mt = 0; mt < 4; ++mt)
                #pragma unroll
                for (int g = 0; g < 2; ++g) {
                    floatx4 z = floatx4{0.f, 0.f, 0.f, 0.f};
                    z = MFMA16(a0[mt], bq0[g], z);
                    s[mt][g] = MFMA16(a1[mt], bq1[g], z);
                }
            // V-frags issued now; latency hides behind softmax
            #pragma unroll
            for (int mt = 0; mt < 4; ++mt) {
                a0[mt] = *(const half8*)(Vt + ((size_t)(mt * 2)     * 64 + lane) * 8);
                a1[mt] = *(const half8*)(Vt + ((size_t)(mt * 2 + 1) * 64 + lane) * 8);
            }

            if (kt == nk - 1) {                       // causal mask (diag tile)
                #pragma unroll
                for (int mt = 0; mt < 4; ++mt)
                    #pragma unroll
                    for (int g = 0; g < 2; ++g)
                        #pragma unroll
                        for (int r = 0; r < 4; ++r)
                            if (kb + mt * 16 + q * 4 + r > row0 + g * 16 + c)
                                s[mt][g][r] = -3.0e38f;
            }

            // online softmax per q-group; P stays in regs as 16x16x16 B-frags
            half4_ ph[2][4];
            #pragma unroll
            for (int g = 0; g < 2; ++g) {
                float mx = s[0][g][0];
                #pragma unroll
                for (int mt = 0; mt < 4; ++mt)
                    #pragma unroll
                    for (int r = 0; r < 4; ++r) mx = fmaxf(mx, s[mt][g][r]);
                mx = fmaxf(mx, __shfl_xor(mx, 16, 64));
                mx = fmaxf(mx, __shfl_xor(mx, 32, 64));
                const float mn    = fmaxf(m[g], mx);
                const float alpha = exp2f(m[g] - mn);
                float sl = 0.f;
                #pragma unroll
                for (int mt = 0; mt < 4; ++mt)
                    #pragma unroll
                    for (int r = 0; r < 4; ++r) {
                        const float ev = exp2f(s[mt][g][r] - mn);
                        sl += ev;
                        ph[g][mt][r] = (_Float16)ev;
                    }
                sl += __shfl_xor(sl, 16, 64);
                sl += __shfl_xor(sl, 32, 64);
                l[g] = l[g] * alpha + sl;
                m[g] = mn;
                #pragma unroll
                for (int mt = 0; mt < 4; ++mt) o[mt][g] *= alpha;
            }

            // O^T += V^T · P^T as 4 key-chunk 16x16x16 MFMAs per o-tile
            #pragma unroll
            for (int mt = 0; mt < 4; ++mt) {
                const half4_ v0 = LO4(a0[mt]);
                const half4_ v1 = HI4(a0[mt]);
                const half4_ v2 = LO4(a1[mt]);
                const half4_ v3 = HI4(a1[mt]);
                #pragma unroll
                for (int g = 0; g < 2; ++g) {
                    o[mt][g] = MFMA16K(v0, ph[g][0], o[mt][g]);
                    o[mt][g] = MFMA16K(v1, ph[g][1], o[mt][g]);
                    o[mt][g] = MFMA16K(v2, ph[g][2], o[mt][g]);
                    o[mt][g] = MFMA16K(v3, ph[g][3], o[mt][g]);
                }
            }
        }

        // ---- in-block combine (8 waves), write unnormalized partial ------
        __syncthreads();
        if (q == 0) { Ml[w * 32 + c] = m[0]; Ml[w * 32 + 16 + c] = m[1]; }
        __syncthreads();
        float M0 = Ml[c], M1 = Ml[16 + c];
        #pragma unroll
        for (int w2 = 1; w2 < 8; ++w2) {
            M0 = fmaxf(M0, Ml[w2 * 32 + c]);
            M1 = fmaxf(M1, Ml[w2 * 32 + 16 + c]);
        }
        const float alpha0 = exp2f(m[0] - M0);        // 0 for empty waves
        const float alpha1 = exp2f(m[1] - M1);
        if (q == 0) { Ll[w * 32 + c] = l[0] * alpha0; Ll[w * 32 + 16 + c] = l[1] * alpha1; }

        const int h0 = w * 8 + q * 2;                 // this thread's h slice
        float* Obase = Opart + (size_t)item * 2048;
        #pragma unroll
        for (int gp = 0; gp < 2; ++gp) {
            const float a = gp ? alpha1 : alpha0;
            #pragma unroll
            for (int mt = 0; mt < 4; ++mt)
                #pragma unroll
                for (int r = 0; r < 4; ++r)
                    Ol[w * 1088 + (mt * 16 + q * 4 + r) * 17 + c] = o[mt][gp][r] * a;
            __syncthreads();
            float L = 0.f;
            #pragma unroll
            for (int w2 = 0; w2 < 8; ++w2) L += Ll[w2 * 32 + gp * 16 + c];
            if (w == 0 && q == 0) {
                Mp[(size_t)item * 32 + gp * 16 + c] = gp ? M1 : M0;
                Lp[(size_t)item * 32 + gp * 16 + c] = L;
            }
            float ox = 0.f, oy = 0.f;
            #pragma unroll
            for (int w2 = 0; w2 < 8; ++w2) {
                ox += Ol[w2 * 1088 + h0 * 17 + c];
                oy += Ol[w2 * 1088 + (h0 + 1) * 17 + c];
            }
            float2 st; st.x = ox; st.y = oy;          // unnormalized partial
            *(float2*)(Obase + (size_t)(gp * 16 + c) * 64 + h0) = st;
            __syncthreads();                          // LDS reuse (next gp/pass)
        }
    }
}

// ---------------------------------------------------------------------------
// Kernel 4: merge the 4 split-K partials per q-tile, normalize, write out.
// Grid 512 blocks x 256 thr; thread -> (qrow = tid>>3, h0 = (tid&7)*8).
// ---------------------------------------------------------------------------
__global__ __launch_bounds__(256) void combine_kn(
    const float* __restrict__ Opart, const float* __restrict__ Mp,
    const float* __restrict__ Lp, float* __restrict__ out)
{
    const int cb   = blockIdx.x;                      // 0..511
    const int b    = cb & 3, t32 = cb >> 2;
    const int tid  = threadIdx.x;
    const int qrow = tid >> 3;                        // 0..31
    const int h0   = (tid & 7) * 8;                   // 0..56
    const int it0  = (127 - t32) * 16 + b * 4;        // 4 consecutive items

    float Mv[4], Lv[4];
    #pragma unroll
    for (int p = 0; p < 4; ++p) {
        Mv[p] = Mp[(size_t)(it0 + p) * 32 + qrow];
        Lv[p] = Lp[(size_t)(it0 + p) * 32 + qrow];
    }
    float M = fmaxf(fmaxf(Mv[0], Mv[1]), fmaxf(Mv[2], Mv[3]));
    float L = 0.f;
    floatx4 acc0 = floatx4{0.f, 0.f, 0.f, 0.f};
    floatx4 acc1 = floatx4{0.f, 0.f, 0.f, 0.f};
    #pragma unroll
    for (int p = 0; p < 4; ++p) {
        const float a = exp2f(Mv[p] - M);             // 0 for empty chunks
        L += Lv[p] * a;
        const floatx4* src = (const floatx4*)(Opart + (size_t)(it0 + p) * 2048
                                              + (size_t)qrow * 64 + h0);
        acc0 += src[0] * a;
        acc1 += src[1] * a;
    }
    const float inv = 1.f / L;
    floatx4* dst = (floatx4*)(out + (size_t)(b * T_ + t32 * 32 + qrow) * 64 + h0);
    dst[0] = acc0 * inv;
    dst[1] = acc1 * inv;
}

extern "C" void kernel_launch(void* const* d_in, const int* in_sizes, int n_in,
                              void* d_out, int out_size, void* d_ws, size_t ws_size,
                              hipStream_t stream) {
    const float* x  = (const float*)d_in[0];
    const float* Wq = (const float*)d_in[1];
    const float* Wk = (const float*)d_in[2];
    const float* Wv = (const float*)d_in[3];
    float* out = (float*)d_out;

    _Float16* ws = (_Float16*)d_ws;
    _Float16* Wt2 = ws;                               //   192*1024 = 196608 halfs
    _Float16* Qh  = ws + 196608;                      // 16384*64  = 1048576
    _Float16* Kpk = Qh + 1048576;                     // [4][64][4096]
    _Float16* Vpk = Kpk + 1048576;                    // [4][64][4096]
    float* Opart = (float*)(ws + 3342336);            // [2048][32][64] f32 = 16 MB
    float* Mp    = Opart + 4194304;                   // [2048][32]
    float* Lp    = Mp + 65536;                        // [2048][32]

    hipLaunchKernelGGL(pack_w_kn, dim3(768), dim3(256), 0, stream,
                       Wq, Wk, Wv, Wt2);
    hipLaunchKernelGGL(qkv_kn, dim3((B_ * T_) / 32), dim3(512), 0, stream,
                       x, Wt2, Qh, Kpk, Vpk);
    hipLaunchKernelGGL(attn_kn, dim3(1024), dim3(512), 0, stream,
                       Qh, Kpk, Vpk, Opart, Mp, Lp);
    hipLaunchKernelGGL(combine_kn, dim3(512), dim3(256), 0, stream,
                       Opart, Mp, Lp, out);
}

// Round 8
// 137.950 us; speedup vs baseline: 2.3025x; 1.4024x over previous
//
#include <hip/hip_runtime.h>

#define B_ 4
#define T_ 4096
#define C_ 1024
#define H_ 64

typedef _Float16 half8  __attribute__((ext_vector_type(8)));
typedef _Float16 half4_ __attribute__((ext_vector_type(4)));
typedef float    floatx4 __attribute__((ext_vector_type(4)));

#define MFMA16(a, b, c)  __builtin_amdgcn_mfma_f32_16x16x32_f16(a, b, c, 0, 0, 0)
#define MFMA16K(a, b, c) __builtin_amdgcn_mfma_f32_16x16x16f16(a, b, c, 0, 0, 0)
#define LO4(v) __builtin_shufflevector(v, v, 0, 1, 2, 3)
#define HI4(v) __builtin_shufflevector(v, v, 4, 5, 6, 7)

// ---------------------------------------------------------------------------
// Kernel 1: pack W into MFMA-fragment order (lane-contiguous A-frags).
// ---------------------------------------------------------------------------
__global__ __launch_bounds__(256) void pack_w_kn(
    const float* __restrict__ Wq, const float* __restrict__ Wk,
    const float* __restrict__ Wv, _Float16* __restrict__ Wt2)
{
    const int idx  = blockIdx.x * 256 + threadIdx.x;  // 0 .. 196607
    const int mt   = idx >> 14;
    const int j    = (idx >> 10) & 15;
    const int f    = (idx >> 9) & 1;
    const int lane = (idx >> 3) & 63;
    const int jj   = idx & 7;
    const int q = lane >> 4, c = lane & 15;
    const int k  = j * 64 + f * 32 + q * 8 + jj;
    const int hp = mt * 16 + c;                       // 0..191
    const float* W = (hp < 64) ? Wq : (hp < 128) ? Wk : Wv;
    Wt2[idx] = (_Float16)W[k * H_ + (hp & 63)];
}

// ---------------------------------------------------------------------------
// Kernel 2: fused QKV projection (unchanged).  Vpk in 16x16x16 A-frag order.
// ---------------------------------------------------------------------------
__global__ __launch_bounds__(512) void qkv_kn(
    const float* __restrict__ x, const _Float16* __restrict__ Wt2,
    _Float16* __restrict__ Qh, _Float16* __restrict__ Kpk,
    _Float16* __restrict__ Vpk)
{
    __shared__ _Float16 xs[2][32][72];                // 9216 B
    const int tid  = threadIdx.x;
    const int lane = tid & 63, w = tid >> 6;
    const int q    = lane >> 4, c = lane & 15;
    const int nt   = w & 1;                           // n-half (16 rows)
    const int mg   = w >> 1;                          // m-group (3 m-tiles)
    const int row0 = blockIdx.x * 32;

    const int srow = tid >> 4, scol = (tid & 15) * 4;
    const float* xg = x + (size_t)(row0 + srow) * C_ + scol;

    floatx4 acc[3];
    #pragma unroll
    for (int i = 0; i < 3; ++i) acc[i] = floatx4{0.f, 0.f, 0.f, 0.f};

    float4 g = *(const float4*)xg;                    // preload tile 0

    for (int j = 0; j < 16; ++j) {
        half4_ hv;
        hv[0] = (_Float16)g.x; hv[1] = (_Float16)g.y;
        hv[2] = (_Float16)g.z; hv[3] = (_Float16)g.w;
        *(half4_*)(&xs[j & 1][srow][scol]) = hv;
        __syncthreads();
        if (j < 15) g = *(const float4*)(xg + (j + 1) * 64);

        const _Float16* xrow = &xs[j & 1][nt * 16 + c][q * 8];
        const half8 b0 = *(const half8*)xrow;
        const half8 b1 = *(const half8*)(xrow + 32);

        half8 a[6];
        #pragma unroll
        for (int i = 0; i < 3; ++i) {
            const size_t fb = ((size_t)((mg * 3 + i) * 16 + j) * 2) * 512 + lane * 8;
            a[i * 2]     = *(const half8*)(Wt2 + fb);
            a[i * 2 + 1] = *(const half8*)(Wt2 + fb + 512);
        }
        #pragma unroll
        for (int i = 0; i < 3; ++i) {
            acc[i] = MFMA16(a[i * 2],     b0, acc[i]);
            acc[i] = MFMA16(a[i * 2 + 1], b1, acc[i]);
        }
    }

    const int row = row0 + nt * 16 + c;
    const int b = row >> 12, t4 = row & (T_ - 1);
    const int kt = t4 >> 6;
    const size_t tbase = ((size_t)b * 64 + kt) * 4096;
    const int mtk = (t4 >> 4) & 3;
    const int kk  = t4 & 63;

    #pragma unroll
    for (int i = 0; i < 3; ++i) {
        const int gi = mg * 3 + i;
        if (gi < 4) {                                 // Q row-major
            half4_ v;
            #pragma unroll
            for (int r = 0; r < 4; ++r) v[r] = (_Float16)acc[i][r];
            *(half4_*)(Qh + (size_t)row * H_ + gi * 16 + q * 4) = v;
        } else if (gi < 8) {                          // K fragment-packed (16x16x32 A-frag)
            half4_ v;
            #pragma unroll
            for (int r = 0; r < 4; ++r) v[r] = (_Float16)acc[i][r];
            const int e  = gi - 4;
            const int f  = e >> 1;
            const int qa = (e * 2 + (q >> 1)) & 3;
            *(half4_*)(Kpk + tbase + ((size_t)(mtk * 2 + f) * 64 + qa * 16 + c) * 8
                       + (q & 1) * 4) = v;
        } else {                                      // V 16x16x16 A-frag packed
            const int mtv = gi - 8;
            const int qa2 = (kk >> 2) & 3;
            const int h4  = (kk >> 4) & 1;
            const int f2  = kk >> 5;
            const int i2  = kk & 3;
            #pragma unroll
            for (int r = 0; r < 4; ++r) {
                const int cv = q * 4 + r;             // h & 15
                Vpk[tbase + ((size_t)(mtv * 2 + f2) * 64 + qa2 * 16 + cv) * 8
                    + h4 * 4 + i2] = (_Float16)acc[i][r];
            }
        }
    }
}

// ---------------------------------------------------------------------------
// Kernel 3: causal flash attention — round-1 skeleton (QBLK=16, 1024 blocks,
// 8-way in-block split-K, direct out) with the round-7 post-mortem fixes:
//  * Occupancy is register-capped at 4 waves/SIMD (64 VGPR + ~64 AGPR = 128);
//    QBLK=32's ~140-reg live set spilled ~130 KB/block to scratch every round
//    since r5 (WRITE_SIZE 74-147 MB vs <17 MB real output).  QBLK=16 +
//    P-in-register PV peaks at ~112 regs -> fits 128, zero spill.
//  * K(kt+8) prefetched into the just-freed K regs right after QK; V issued
//    right after QK: both latencies hide under softmax+PV.  #pragma unroll 1
//    keeps the compiler from doubling pressure.
//  * T13 defer-rescale (skip o-rescale while max grows < 8 log2-units).
//  * T5 s_setprio(1) around MFMA clusters.
// ---------------------------------------------------------------------------
__global__ __launch_bounds__(512, 4) void attn_kn(
    const _Float16* __restrict__ Qh, const _Float16* __restrict__ Kpk,
    const _Float16* __restrict__ Vpk, float* __restrict__ out)
{
    __shared__ __align__(16) char smem[36864];
    const int lane = threadIdx.x & 63;
    const int w    = threadIdx.x >> 6;                // 0..7
    const int q    = lane >> 4, c = lane & 15;

    // XCD-aware decode: batch per XCD pair, heavy tiles first (round-1 map)
    const int bid  = blockIdx.x;
    const int xcd  = bid & 7;
    const int slot = bid >> 3;                        // 0..127
    const int b    = xcd >> 1;
    const int t    = 255 - ((slot << 1) | (xcd & 1));
    const int row0 = t * 16;
    const int grow = b * T_ + row0;
    const int nk   = (t >> 2) + 1;                    // 64-key tiles (last=diag)

    // Q B-frag, pre-scaled by (1/8)*log2(e)
    half8 bq0 = *(const half8*)(Qh + (size_t)(grow + c) * H_ + q * 8);
    half8 bq1 = *(const half8*)(Qh + (size_t)(grow + c) * H_ + 32 + q * 8);
    const _Float16 qs = (_Float16)0.18033688f;
    bq0 *= qs; bq1 *= qs;

    floatx4 o[4];
    #pragma unroll
    for (int i = 0; i < 4; ++i) o[i] = floatx4{0.f, 0.f, 0.f, 0.f};
    float m = -3.0e38f, l = 0.f;

    const _Float16* Kb = Kpk + (size_t)b * 262144;    // b * 64 * 4096
    const _Float16* Vb = Vpk + (size_t)b * 262144;

    half8 k0[4], k1[4], v0[4], v1[4];
    {   // preload K for this wave's first tile (kt = w; always in-bounds)
        const _Float16* Kt = Kb + (size_t)w * 4096;
        #pragma unroll
        for (int mt = 0; mt < 4; ++mt) {
            k0[mt] = *(const half8*)(Kt + ((mt * 2)     * 64 + lane) * 8);
            k1[mt] = *(const half8*)(Kt + ((mt * 2 + 1) * 64 + lane) * 8);
        }
    }

    #pragma unroll 1
    for (int kt = w; kt < nk; kt += 8) {
        const int kb = kt * 64;

        // QK^T: 64 keys x 16 q
        floatx4 s[4];
        __builtin_amdgcn_s_setprio(1);
        #pragma unroll
        for (int mt = 0; mt < 4; ++mt) {
            floatx4 z = floatx4{0.f, 0.f, 0.f, 0.f};
            z = MFMA16(k0[mt], bq0, z);
            s[mt] = MFMA16(k1[mt], bq1, z);
        }
        __builtin_amdgcn_s_setprio(0);

        // V(kt): latency hides under softmax
        const _Float16* Vt = Vb + (size_t)kt * 4096;
        #pragma unroll
        for (int mt = 0; mt < 4; ++mt) {
            v0[mt] = *(const half8*)(Vt + ((mt * 2)     * 64 + lane) * 8);
            v1[mt] = *(const half8*)(Vt + ((mt * 2 + 1) * 64 + lane) * 8);
        }
        // K(kt+8) prefetch into the just-freed K regs (clamped on last iter)
        {
            const int ktn = (kt + 8 < nk) ? (kt + 8) : kt;
            const _Float16* Kt = Kb + (size_t)ktn * 4096;
            #pragma unroll
            for (int mt = 0; mt < 4; ++mt) {
                k0[mt] = *(const half8*)(Kt + ((mt * 2)     * 64 + lane) * 8);
                k1[mt] = *(const half8*)(Kt + ((mt * 2 + 1) * 64 + lane) * 8);
            }
        }

        if (kt == nk - 1) {                           // causal mask (diag tile)
            #pragma unroll
            for (int mt = 0; mt < 4; ++mt)
                #pragma unroll
                for (int r = 0; r < 4; ++r)
                    if (kb + mt * 16 + q * 4 + r > row0 + c) s[mt][r] = -3.0e38f;
        }

        // online softmax, lane holds 16 scores of ONE q-row; defer-rescale
        float mx = s[0][0];
        #pragma unroll
        for (int mt = 0; mt < 4; ++mt)
            #pragma unroll
            for (int r = 0; r < 4; ++r) mx = fmaxf(mx, s[mt][r]);
        mx = fmaxf(mx, __shfl_xor(mx, 16, 64));
        mx = fmaxf(mx, __shfl_xor(mx, 32, 64));
        if (!__all(mx <= m + 8.f)) {                  // T13: rescale only on growth
            const float mn    = fmaxf(m, mx);
            const float alpha = exp2f(m - mn);
            l *= alpha;
            #pragma unroll
            for (int mt = 0; mt < 4; ++mt) o[mt] *= alpha;
            m = mn;
        }
        half4_ ph[4];
        float sl = 0.f;
        #pragma unroll
        for (int mt = 0; mt < 4; ++mt)
            #pragma unroll
            for (int r = 0; r < 4; ++r) {
                const float ev = exp2f(s[mt][r] - m);
                sl += ev;
                ph[mt][r] = (_Float16)ev;
            }
        sl += __shfl_xor(sl, 16, 64);
        sl += __shfl_xor(sl, 32, 64);
        l += sl;

        // O^T += V^T · P^T (P stays in registers as 16x16x16 B-frags)
        __builtin_amdgcn_s_setprio(1);
        #pragma unroll
        for (int mt = 0; mt < 4; ++mt) {
            o[mt] = MFMA16K(LO4(v0[mt]), ph[0], o[mt]);
            o[mt] = MFMA16K(HI4(v0[mt]), ph[1], o[mt]);
            o[mt] = MFMA16K(LO4(v1[mt]), ph[2], o[mt]);
            o[mt] = MFMA16K(HI4(v1[mt]), ph[3], o[mt]);
        }
        __builtin_amdgcn_s_setprio(0);
    }

    // ---- flash combine across the 8 waves (direct out write) -------------
    float* Ol = (float*)smem;                         // [8][1088] (pad 17)
    float* Ml = (float*)(smem + 34816);               // [8][16]
    float* Ll = (float*)(smem + 35328);               // [8][16]
    if (q == 0) Ml[w * 16 + c] = m;
    __syncthreads();
    float M = Ml[c];
    #pragma unroll
    for (int w2 = 1; w2 < 8; ++w2) M = fmaxf(M, Ml[w2 * 16 + c]);
    const float alpha = exp2f(m - M);                 // 0 for empty waves
    if (q == 0) Ll[w * 16 + c] = l * alpha;
    #pragma unroll
    for (int mt = 0; mt < 4; ++mt)
        #pragma unroll
        for (int r = 0; r < 4; ++r)
            Ol[w * 1088 + (mt * 16 + q * 4 + r) * 17 + c] = o[mt][r] * alpha;
    __syncthreads();

    float L = 0.f;
    #pragma unroll
    for (int w2 = 0; w2 < 8; ++w2) L += Ll[w2 * 16 + c];
    const float inv = 1.f / L;
    const int h0 = w * 8 + q * 2;
    float ox = 0.f, oy = 0.f;
    #pragma unroll
    for (int w2 = 0; w2 < 8; ++w2) {
        ox += Ol[w2 * 1088 + h0 * 17 + c];
        oy += Ol[w2 * 1088 + (h0 + 1) * 17 + c];
    }
    float2 st; st.x = ox * inv; st.y = oy * inv;
    *(float2*)(out + (size_t)(grow + c) * H_ + h0) = st;
}

extern "C" void kernel_launch(void* const* d_in, const int* in_sizes, int n_in,
                              void* d_out, int out_size, void* d_ws, size_t ws_size,
                              hipStream_t stream) {
    const float* x  = (const float*)d_in[0];
    const float* Wq = (const float*)d_in[1];
    const float* Wk = (const float*)d_in[2];
    const float* Wv = (const float*)d_in[3];
    float* out = (float*)d_out;

    _Float16* ws = (_Float16*)d_ws;
    _Float16* Wt2 = ws;                               //   192*1024 = 196608
    _Float16* Qh  = ws + 196608;                      // 16384*64  = 1048576
    _Float16* Kpk = Qh + 1048576;                     // [4][64][4096]
    _Float16* Vpk = Kpk + 1048576;                    // [4][64][4096]

    hipLaunchKernelGGL(pack_w_kn, dim3(768), dim3(256), 0, stream, Wq, Wk, Wv, Wt2);
    hipLaunchKernelGGL(qkv_kn, dim3((B_ * T_) / 32), dim3(512), 0, stream,
                       x, Wt2, Qh, Kpk, Vpk);
    hipLaunchKernelGGL(attn_kn, dim3(1024), dim3(512), 0, stream,
                       Qh, Kpk, Vpk, out);
}